// Round 3
// baseline (3560.925 us; speedup 1.0000x reference)
//
#include <hip/hip_runtime.h>
#include <hip/hip_bf16.h>

typedef __attribute__((ext_vector_type(8))) short s16x8;
typedef __attribute__((ext_vector_type(4))) float f32x4;

#define MFMA_B16(a, b, c) __builtin_amdgcn_mfma_f32_16x16x32_bf16((a), (b), (c), 0, 0, 0)

static __device__ __forceinline__ short f2bf(float f) {
    __hip_bfloat16 h = __float2bfloat16(f);
    return __builtin_bit_cast(short, h);
}
static __device__ __forceinline__ float rcp_f(float x) {
    return __builtin_amdgcn_rcpf(x);
}

// pre-pass: X fp32 -> bf16 in workspace
__global__ void xcvt_kernel(const float* __restrict__ X, short* __restrict__ Xb, int n) {
    int i = (blockIdx.x * 256 + threadIdx.x) * 4;
    if (i < n) {
        float4 v = *(const float4*)(X + i);
        short4 o;
        o.x = f2bf(v.x); o.y = f2bf(v.y); o.z = f2bf(v.z); o.w = f2bf(v.w);
        *(short4*)(Xb + i) = o;
    }
}

// Ensemble LSTM. R12 = batch-split-16: WG = (series n, batch-pair). 512 WGs, 2 WGs/CU.
// Rationale: counters show VALUBusy ~= MfmaUtil (MFMA is VALU-class in the fallback
// formula) -> real scalar VALU is tiny; step = 1548cy with only ~660cy MFMA issue per
// SIMD and ~850cy latency idle (ds_read -> 4-deep MFMA chain -> transcendental epilogue
// -> barrier) that 2 waves/SIMD cannot hide. A second INDEPENDENT WG per CU interleaves
// its serial path into that idle. Per-WG structure is byte-identical to R10 (330 us);
// only batch mapping, guards, grid change. M-rows 2/16 used: M-waste is free when
// latency-bound.
// Journal:
//   R5/R6 x-pair packing     -> +15 us (lengthened C-operand serial chain)
//   R7 lgkm-only asm barrier -> +21 us (defeated compiler scheduling)
//   R8 LDS atomicAdd pred    -> +834 us (not fire-and-forget)
//   R10 acc ping-pong + early vmem issue -> neutral (no second wave to fill holes)
//   R11 masked compact LDS + 2+2 chains  -> +105 us (conflicts -89% but scheduling
//        damaged; conflicts were never on the critical path). Reverted.
template<bool BF16X>
__global__ __launch_bounds__(512, 4)
void clstm_kernel(const float* __restrict__ X,
                  const short* __restrict__ Xb,
                  const float* __restrict__ W_ih,
                  const float* __restrict__ W_hh,
                  const float* __restrict__ b_ih,
                  const float* __restrict__ b_hh,
                  const float* __restrict__ W_out,
                  const float* __restrict__ b_out,
                  float* __restrict__ out)
{
    constexpr int B = 32, T = 512, N = 32, H = 128, G = 512;  // G = 4H
    constexpr int HT_OFF = B * T * N;
    constexpr int CT_OFF = HT_OFF + N * B * H;
    constexpr int PRED_OFF = 8192;               // 2 x 4KB h frag buffers below
    constexpr float C1 = 1.4426950408889634f;    // log2(e)

    __shared__ __align__(16) unsigned char smem[8192 + 4096];  // h dbuf + pred stage

    const int tid  = threadIdx.x;
    const int w    = tid >> 6;   // wave 0..7
    const int L    = tid & 63;
    const int col  = L & 15;
    const int quad = L >> 4;
    const int n    = blockIdx.x & 31;   // series
    const int bgrp = blockIdx.x >> 5;   // batch pair 0..15 (2 batches each)

    // ---- loop-invariant weight fragments (fp32 -> bf16, once) ----
    s16x8 Bh[4][4];  // [gate tt][kt]
    s16x8 Bx[4];     // [gate tt]  k = input p 0..31
    f32x4 biasv[4];  // persistent MFMA C operand (bias broadcast)
#pragma unroll
    for (int tt = 0; tt < 4; ++tt) {
        const int g = (w + 8 * tt) * 16 + col;
        const float* whr = W_hh + ((size_t)n * G + g) * H + quad * 8;
#pragma unroll
        for (int kt = 0; kt < 4; ++kt) {
            const float* p = whr + kt * 32;
#pragma unroll
            for (int jj = 0; jj < 8; ++jj) Bh[tt][kt][jj] = f2bf(p[jj]);
        }
        const float* wir = W_ih + ((size_t)n * G + g) * N + quad * 8;
#pragma unroll
        for (int jj = 0; jj < 8; ++jj) Bx[tt][jj] = f2bf(wir[jj]);
        const float bb = b_ih[n * G + g] + b_hh[n * G + g];
        biasv[tt] = (f32x4){bb, bb, bb, bb};
    }

    // ---- pred tile: B col 0 = W_out, rotated across waves ----
    s16x8 Bp[4];
    const float bo = b_out[n];
    const f32x4 bov = (f32x4){bo, bo, bo, bo};
#pragma unroll
    for (int kt = 0; kt < 4; ++kt) {
        const float* wp = W_out + n * H + kt * 32 + quad * 8;
#pragma unroll
        for (int jj = 0; jj < 8; ++jj)
            Bp[kt][jj] = (col == 0) ? f2bf(wp[jj]) : (short)0;
    }

    // ---- h writer offset: cell (batch=quad -> m=4*quad, j=w*16+col) ----
    // only quad<2 carries a real batch now; rows 8,12 stay zero-pad.
    int wboff;
    {
        const int j = w * 16 + col;
        wboff = (j >> 5) * 1024 + (((((j >> 3) & 3) << 4) | (quad << 2)) * 16) + (j & 7) * 2;
    }
    const bool cellactive = (quad < 2);

    // ---- x loader: lanes col in {0,4} carry batch b=col>>2 at row m=col ----
    const bool xactive = ((col & 3) == 0) && (col < 8);
    const int  xb      = bgrp * 2 + (col >> 2);   // global batch 0..31
    const float* xp  = X + ((size_t)xb * T) * N + quad * 8;
    const short* xbp = BF16X ? (Xb + ((size_t)xb * T) * N + quad * 8) : nullptr;

    auto loadx = [&](int t) -> s16x8 {
        s16x8 r = (s16x8)(short)0;
        if (xactive) {
            if constexpr (BF16X) {
                r = *(const s16x8*)(xbp + (size_t)t * N);
            } else {
                float4 lo = *(const float4*)(xp + (size_t)t * N);
                float4 hi = *(const float4*)(xp + (size_t)t * N + 4);
                r[0] = f2bf(lo.x); r[1] = f2bf(lo.y); r[2] = f2bf(lo.z); r[3] = f2bf(lo.w);
                r[4] = f2bf(hi.x); r[5] = f2bf(hi.y); r[6] = f2bf(hi.z); r[7] = f2bf(hi.w);
            }
        }
        return r;
    };

    // zero both h frag buffers (pad rows must stay 0); pred stage fully written later
    *(float4*)(smem + tid * 16) = make_float4(0.f, 0.f, 0.f, 0.f);

    float cst = 0.f, hlast = 0.f;

    // prologue: accA = partial gates for t=0; prefetch x_1, x_2
    f32x4 accA[4], accB[4];
    {
        s16x8 x0 = loadx(0);
#pragma unroll
        for (int tt = 0; tt < 4; ++tt)
            accA[tt] = MFMA_B16(x0, Bx[tt], biasv[tt]);
    }
    s16x8 xA = loadx(1);
    s16x8 xB = loadx(2);

    __syncthreads();

// CUR holds x-partials (+bias) for TCUR on entry; gates accumulate in place.
// NXT computed fresh (x-partials for TCUR+1), issued first to fill the lgkm window.
#define STEP(P, TCUR, CUR, NXT)                                                     \
    {                                                                               \
        const unsigned char* rb = smem + (P) * 4096;                                \
        s16x8 Af[4];                                                                \
        _Pragma("unroll")                                                           \
        for (int kt = 0; kt < 4; ++kt)                                              \
            Af[kt] = *(const s16x8*)(rb + kt * 1024 + L * 16);                      \
        _Pragma("unroll")                                                           \
        for (int tt = 0; tt < 4; ++tt)                                              \
            NXT[tt] = MFMA_B16(xA, Bx[tt], biasv[tt]);                              \
        xA = xB;                                                                    \
        xB = loadx(((TCUR) + 3 < T) ? (TCUR) + 3 : T - 1);                          \
        _Pragma("unroll")                                                           \
        for (int tt = 0; tt < 4; ++tt)                                              \
            CUR[tt] = MFMA_B16(Af[0], Bh[tt][0], CUR[tt]);                          \
        _Pragma("unroll")                                                           \
        for (int kt = 1; kt < 4; ++kt) {                                            \
            _Pragma("unroll")                                                       \
            for (int tt = 0; tt < 4; ++tt)                                          \
                CUR[tt] = MFMA_B16(Af[kt], Bh[tt][kt], CUR[tt]);                    \
        }                                                                           \
        if (w == ((TCUR) & 7)) {                                                    \
            f32x4 pacc = bov;                                                       \
            _Pragma("unroll")                                                       \
            for (int kt = 0; kt < 4; ++kt)                                          \
                pacc = MFMA_B16(Af[kt], Bp[kt], pacc);                              \
            if ((TCUR) > 0 && col == 0 && cellactive)                               \
                *(float*)(smem + PRED_OFF + ((quad << 9) + (TCUR) - 1) * 4) =       \
                    pacc[0];                                                        \
        }                                                                           \
        /* epilogue: fused-rcp activations (8 trans) */                             \
        {                                                                           \
            const float iv = CUR[0][0], fv = CUR[1][0];                             \
            const float gv = CUR[2][0], ov = CUR[3][0];                             \
            const float ei = exp2f(-C1 * iv);                                       \
            const float ef = exp2f(-C1 * fv);                                       \
            const float eg = exp2f(-2.0f * C1 * gv);                                \
            const float eo = exp2f(-C1 * ov);                                       \
            const float sf = rcp_f(1.0f + ef);                                      \
            const float itg = (1.0f - eg) * rcp_f((1.0f + ei) * (1.0f + eg));       \
            const float cc = __builtin_fmaf(sf, cst, itg);                          \
            cst = cc;                                                               \
            const float ec = exp2f(-2.0f * C1 * cc);                                \
            const float hv = (1.0f - ec) * rcp_f((1.0f + eo) * (1.0f + ec));        \
            hlast = hv;                                                             \
            if (cellactive)                                                         \
                *(short*)(smem + ((P) ^ 1) * 4096 + wboff) = f2bf(hv);              \
        }                                                                           \
        __syncthreads();                                                            \
    }

#pragma unroll 1
    for (int t2 = 0; t2 < T; t2 += 2) {
        STEP(0, t2, accA, accB)
        STEP(1, t2 + 1, accB, accA)
    }
#undef STEP

    // ---- tail pred: t = T-1 uses h_{T-1}, sitting in buffer 0 ----
    if (w == 0) {
        f32x4 pacc = bov;
#pragma unroll
        for (int kt = 0; kt < 4; ++kt) {
            s16x8 Af = *(const s16x8*)(smem + kt * 1024 + L * 16);
            pacc = MFMA_B16(Af, Bp[kt], pacc);
        }
        if (col == 0 && cellactive)
            *(float*)(smem + PRED_OFF + ((quad << 9) + (T - 1)) * 4) = pacc[0];
    }
    __syncthreads();

    // ---- flush pred stage -> global: 2 batches x T ----
#pragma unroll
    for (int e = tid; e < 2 * T; e += 512) {
        const int b = e >> 9, t = e & (T - 1);
        out[((size_t)(bgrp * 2 + b) * T + t) * N + n] =
            *(const float*)(smem + PRED_OFF + e * 4);
    }

    // ---- final hT, cT ----
    if (cellactive) {
        const int bglob = bgrp * 2 + quad;
        const int j = w * 16 + col;
        out[HT_OFF + ((size_t)n * B + bglob) * H + j] = hlast;
        out[CT_OFF + ((size_t)n * B + bglob) * H + j] = cst;
    }
}

extern "C" void kernel_launch(void* const* d_in, const int* in_sizes, int n_in,
                              void* d_out, int out_size, void* d_ws, size_t ws_size,
                              hipStream_t stream) {
    const float* X     = (const float*)d_in[0];
    const float* W_ih  = (const float*)d_in[1];
    const float* W_hh  = (const float*)d_in[2];
    const float* b_ih  = (const float*)d_in[3];
    const float* b_hh  = (const float*)d_in[4];
    const float* W_out = (const float*)d_in[5];
    const float* b_out = (const float*)d_in[6];
    float* out = (float*)d_out;

    const int xelems = 32 * 512 * 32;  // B*T*N
    const bool usebf = ws_size >= (size_t)xelems * sizeof(short);

    if (usebf) {
        short* Xb = (short*)d_ws;
        xcvt_kernel<<<dim3(xelems / 1024), dim3(256), 0, stream>>>(X, Xb, xelems);
        clstm_kernel<true><<<dim3(512), dim3(512), 0, stream>>>(
            X, Xb, W_ih, W_hh, b_ih, b_hh, W_out, b_out, out);
    } else {
        clstm_kernel<false><<<dim3(512), dim3(512), 0, stream>>>(
            X, nullptr, W_ih, W_hh, b_ih, b_hh, W_out, b_out, out);
    }
}

// Round 4
// 648.960 us; speedup vs baseline: 5.4871x; 5.4871x over previous
//
#include <hip/hip_runtime.h>
#include <hip/hip_bf16.h>

typedef __attribute__((ext_vector_type(8))) short s16x8;
typedef __attribute__((ext_vector_type(4))) float f32x4;

#define MFMA_B16(a, b, c) __builtin_amdgcn_mfma_f32_16x16x32_bf16((a), (b), (c), 0, 0, 0)

static __device__ __forceinline__ short f2bf(float f) {
    __hip_bfloat16 h = __float2bfloat16(f);
    return __builtin_bit_cast(short, h);
}
static __device__ __forceinline__ float rcp_f(float x) {
    return __builtin_amdgcn_rcpf(x);
}

// pre-pass: X fp32 -> bf16 in workspace
__global__ void xcvt_kernel(const float* __restrict__ X, short* __restrict__ Xb, int n) {
    int i = (blockIdx.x * 256 + threadIdx.x) * 4;
    if (i < n) {
        float4 v = *(const float4*)(X + i);
        short4 o;
        o.x = f2bf(v.x); o.y = f2bf(v.y); o.z = f2bf(v.z); o.w = f2bf(v.w);
        *(short4*)(Xb + i) = o;
    }
}

// Ensemble LSTM. R13 = batch-split-16 (512 WGs, 2 WGs/CU) with launch_bounds REVERTED
// to (512,2). R12's 10x regression was NOT the concurrency idea: bounds(512,4) capped
// VGPR at 128 and the compiler emitted 64 VGPRs, spilling the whole weight set
// (FETCH 9.3MB -> 11.9GB of scratch traffic). With (512,2) the same code allocates
// 116 VGPRs; HW occupancy from actual usage: 116<=128 -> 4 waves/SIMD -> two 8-wave
// WGs/CU. Grid=512 is what delivers the second WG; the bounds never needed to change.
// Journal:
//   R5/R6 x-pair packing     -> +15 us (lengthened C-operand serial chain)
//   R7 lgkm-only asm barrier -> +21 us (defeated compiler scheduling)
//   R8 LDS atomicAdd pred    -> +834 us (not fire-and-forget)
//   R10 acc ping-pong + early vmem issue -> neutral (no second wave to fill holes)
//   R11 masked compact LDS + 2+2 chains  -> +105 us (conflicts -89% but off critical path)
//   R12 bounds(512,4) + grid 512         -> +3200 us (VGPR 64, full weight spill;
//        occupancy 47.8% proves 2 WGs/CU co-residency works)
template<bool BF16X>
__global__ __launch_bounds__(512, 2)
void clstm_kernel(const float* __restrict__ X,
                  const short* __restrict__ Xb,
                  const float* __restrict__ W_ih,
                  const float* __restrict__ W_hh,
                  const float* __restrict__ b_ih,
                  const float* __restrict__ b_hh,
                  const float* __restrict__ W_out,
                  const float* __restrict__ b_out,
                  float* __restrict__ out)
{
    constexpr int B = 32, T = 512, N = 32, H = 128, G = 512;  // G = 4H
    constexpr int HT_OFF = B * T * N;
    constexpr int CT_OFF = HT_OFF + N * B * H;
    constexpr int PRED_OFF = 8192;               // 2 x 4KB h frag buffers below
    constexpr float C1 = 1.4426950408889634f;    // log2(e)

    __shared__ __align__(16) unsigned char smem[8192 + 4096];  // h dbuf + pred stage

    const int tid  = threadIdx.x;
    const int w    = tid >> 6;   // wave 0..7
    const int L    = tid & 63;
    const int col  = L & 15;
    const int quad = L >> 4;
    const int n    = blockIdx.x & 31;   // series
    const int bgrp = blockIdx.x >> 5;   // batch pair 0..15 (2 batches each)

    // ---- loop-invariant weight fragments (fp32 -> bf16, once) ----
    s16x8 Bh[4][4];  // [gate tt][kt]
    s16x8 Bx[4];     // [gate tt]  k = input p 0..31
    f32x4 biasv[4];  // persistent MFMA C operand (bias broadcast)
#pragma unroll
    for (int tt = 0; tt < 4; ++tt) {
        const int g = (w + 8 * tt) * 16 + col;
        const float* whr = W_hh + ((size_t)n * G + g) * H + quad * 8;
#pragma unroll
        for (int kt = 0; kt < 4; ++kt) {
            const float* p = whr + kt * 32;
#pragma unroll
            for (int jj = 0; jj < 8; ++jj) Bh[tt][kt][jj] = f2bf(p[jj]);
        }
        const float* wir = W_ih + ((size_t)n * G + g) * N + quad * 8;
#pragma unroll
        for (int jj = 0; jj < 8; ++jj) Bx[tt][jj] = f2bf(wir[jj]);
        const float bb = b_ih[n * G + g] + b_hh[n * G + g];
        biasv[tt] = (f32x4){bb, bb, bb, bb};
    }

    // ---- pred tile: B col 0 = W_out, rotated across waves ----
    s16x8 Bp[4];
    const float bo = b_out[n];
    const f32x4 bov = (f32x4){bo, bo, bo, bo};
#pragma unroll
    for (int kt = 0; kt < 4; ++kt) {
        const float* wp = W_out + n * H + kt * 32 + quad * 8;
#pragma unroll
        for (int jj = 0; jj < 8; ++jj)
            Bp[kt][jj] = (col == 0) ? f2bf(wp[jj]) : (short)0;
    }

    // ---- h writer offset: cell (batch=quad -> m=4*quad, j=w*16+col) ----
    // only quad<2 carries a real batch now; rows 8,12 stay zero-pad.
    int wboff;
    {
        const int j = w * 16 + col;
        wboff = (j >> 5) * 1024 + (((((j >> 3) & 3) << 4) | (quad << 2)) * 16) + (j & 7) * 2;
    }
    const bool cellactive = (quad < 2);

    // ---- x loader: lanes col in {0,4} carry batch b=col>>2 at row m=col ----
    const bool xactive = ((col & 3) == 0) && (col < 8);
    const int  xb      = bgrp * 2 + (col >> 2);   // global batch 0..31
    const float* xp  = X + ((size_t)xb * T) * N + quad * 8;
    const short* xbp = BF16X ? (Xb + ((size_t)xb * T) * N + quad * 8) : nullptr;

    auto loadx = [&](int t) -> s16x8 {
        s16x8 r = (s16x8)(short)0;
        if (xactive) {
            if constexpr (BF16X) {
                r = *(const s16x8*)(xbp + (size_t)t * N);
            } else {
                float4 lo = *(const float4*)(xp + (size_t)t * N);
                float4 hi = *(const float4*)(xp + (size_t)t * N + 4);
                r[0] = f2bf(lo.x); r[1] = f2bf(lo.y); r[2] = f2bf(lo.z); r[3] = f2bf(lo.w);
                r[4] = f2bf(hi.x); r[5] = f2bf(hi.y); r[6] = f2bf(hi.z); r[7] = f2bf(hi.w);
            }
        }
        return r;
    };

    // zero both h frag buffers (pad rows must stay 0); pred stage fully written later
    *(float4*)(smem + tid * 16) = make_float4(0.f, 0.f, 0.f, 0.f);

    float cst = 0.f, hlast = 0.f;

    // prologue: accA = partial gates for t=0; prefetch x_1, x_2
    f32x4 accA[4], accB[4];
    {
        s16x8 x0 = loadx(0);
#pragma unroll
        for (int tt = 0; tt < 4; ++tt)
            accA[tt] = MFMA_B16(x0, Bx[tt], biasv[tt]);
    }
    s16x8 xA = loadx(1);
    s16x8 xB = loadx(2);

    __syncthreads();

// CUR holds x-partials (+bias) for TCUR on entry; gates accumulate in place.
// NXT computed fresh (x-partials for TCUR+1), issued first to fill the lgkm window.
#define STEP(P, TCUR, CUR, NXT)                                                     \
    {                                                                               \
        const unsigned char* rb = smem + (P) * 4096;                                \
        s16x8 Af[4];                                                                \
        _Pragma("unroll")                                                           \
        for (int kt = 0; kt < 4; ++kt)                                              \
            Af[kt] = *(const s16x8*)(rb + kt * 1024 + L * 16);                      \
        _Pragma("unroll")                                                           \
        for (int tt = 0; tt < 4; ++tt)                                              \
            NXT[tt] = MFMA_B16(xA, Bx[tt], biasv[tt]);                              \
        xA = xB;                                                                    \
        xB = loadx(((TCUR) + 3 < T) ? (TCUR) + 3 : T - 1);                          \
        _Pragma("unroll")                                                           \
        for (int tt = 0; tt < 4; ++tt)                                              \
            CUR[tt] = MFMA_B16(Af[0], Bh[tt][0], CUR[tt]);                          \
        _Pragma("unroll")                                                           \
        for (int kt = 1; kt < 4; ++kt) {                                            \
            _Pragma("unroll")                                                       \
            for (int tt = 0; tt < 4; ++tt)                                          \
                CUR[tt] = MFMA_B16(Af[kt], Bh[tt][kt], CUR[tt]);                    \
        }                                                                           \
        if (w == ((TCUR) & 7)) {                                                    \
            f32x4 pacc = bov;                                                       \
            _Pragma("unroll")                                                       \
            for (int kt = 0; kt < 4; ++kt)                                          \
                pacc = MFMA_B16(Af[kt], Bp[kt], pacc);                              \
            if ((TCUR) > 0 && col == 0 && cellactive)                               \
                *(float*)(smem + PRED_OFF + ((quad << 9) + (TCUR) - 1) * 4) =       \
                    pacc[0];                                                        \
        }                                                                           \
        /* epilogue: fused-rcp activations (8 trans) */                             \
        {                                                                           \
            const float iv = CUR[0][0], fv = CUR[1][0];                             \
            const float gv = CUR[2][0], ov = CUR[3][0];                             \
            const float ei = exp2f(-C1 * iv);                                       \
            const float ef = exp2f(-C1 * fv);                                       \
            const float eg = exp2f(-2.0f * C1 * gv);                                \
            const float eo = exp2f(-C1 * ov);                                       \
            const float sf = rcp_f(1.0f + ef);                                      \
            const float itg = (1.0f - eg) * rcp_f((1.0f + ei) * (1.0f + eg));       \
            const float cc = __builtin_fmaf(sf, cst, itg);                          \
            cst = cc;                                                               \
            const float ec = exp2f(-2.0f * C1 * cc);                                \
            const float hv = (1.0f - ec) * rcp_f((1.0f + eo) * (1.0f + ec));        \
            hlast = hv;                                                             \
            if (cellactive)                                                         \
                *(short*)(smem + ((P) ^ 1) * 4096 + wboff) = f2bf(hv);              \
        }                                                                           \
        __syncthreads();                                                            \
    }

#pragma unroll 1
    for (int t2 = 0; t2 < T; t2 += 2) {
        STEP(0, t2, accA, accB)
        STEP(1, t2 + 1, accB, accA)
    }
#undef STEP

    // ---- tail pred: t = T-1 uses h_{T-1}, sitting in buffer 0 ----
    if (w == 0) {
        f32x4 pacc = bov;
#pragma unroll
        for (int kt = 0; kt < 4; ++kt) {
            s16x8 Af = *(const s16x8*)(smem + kt * 1024 + L * 16);
            pacc = MFMA_B16(Af, Bp[kt], pacc);
        }
        if (col == 0 && cellactive)
            *(float*)(smem + PRED_OFF + ((quad << 9) + (T - 1)) * 4) = pacc[0];
    }
    __syncthreads();

    // ---- flush pred stage -> global: 2 batches x T ----
#pragma unroll
    for (int e = tid; e < 2 * T; e += 512) {
        const int b = e >> 9, t = e & (T - 1);
        out[((size_t)(bgrp * 2 + b) * T + t) * N + n] =
            *(const float*)(smem + PRED_OFF + e * 4);
    }

    // ---- final hT, cT ----
    if (cellactive) {
        const int bglob = bgrp * 2 + quad;
        const int j = w * 16 + col;
        out[HT_OFF + ((size_t)n * B + bglob) * H + j] = hlast;
        out[CT_OFF + ((size_t)n * B + bglob) * H + j] = cst;
    }
}

extern "C" void kernel_launch(void* const* d_in, const int* in_sizes, int n_in,
                              void* d_out, int out_size, void* d_ws, size_t ws_size,
                              hipStream_t stream) {
    const float* X     = (const float*)d_in[0];
    const float* W_ih  = (const float*)d_in[1];
    const float* W_hh  = (const float*)d_in[2];
    const float* b_ih  = (const float*)d_in[3];
    const float* b_hh  = (const float*)d_in[4];
    const float* W_out = (const float*)d_in[5];
    const float* b_out = (const float*)d_in[6];
    float* out = (float*)d_out;

    const int xelems = 32 * 512 * 32;  // B*T*N
    const bool usebf = ws_size >= (size_t)xelems * sizeof(short);

    if (usebf) {
        short* Xb = (short*)d_ws;
        xcvt_kernel<<<dim3(xelems / 1024), dim3(256), 0, stream>>>(X, Xb, xelems);
        clstm_kernel<true><<<dim3(512), dim3(512), 0, stream>>>(
            X, Xb, W_ih, W_hh, b_ih, b_hh, W_out, b_out, out);
    } else {
        clstm_kernel<false><<<dim3(512), dim3(512), 0, stream>>>(
            X, nullptr, W_ih, W_hh, b_ih, b_hh, W_out, b_out, out);
    }
}

// Round 5
// 361.270 us; speedup vs baseline: 9.8567x; 1.7963x over previous
//
#include <hip/hip_runtime.h>
#include <hip/hip_bf16.h>

typedef __attribute__((ext_vector_type(8))) short s16x8;
typedef __attribute__((ext_vector_type(4))) float f32x4;

#define MFMA_B16(a, b, c) __builtin_amdgcn_mfma_f32_16x16x32_bf16((a), (b), (c), 0, 0, 0)

static __device__ __forceinline__ short f2bf(float f) {
    __hip_bfloat16 h = __float2bfloat16(f);
    return __builtin_bit_cast(short, h);
}
static __device__ __forceinline__ float rcp_f(float x) {
    return __builtin_amdgcn_rcpf(x);
}

// pre-pass: X fp32 -> bf16 in workspace
__global__ void xcvt_kernel(const float* __restrict__ X, short* __restrict__ Xb, int n) {
    int i = (blockIdx.x * 256 + threadIdx.x) * 4;
    if (i < n) {
        float4 v = *(const float4*)(X + i);
        short4 o;
        o.x = f2bf(v.x); o.y = f2bf(v.y); o.z = f2bf(v.z); o.w = f2bf(v.w);
        *(short4*)(Xb + i) = o;
    }
}

// Ensemble LSTM, batch-split-8: WG = (series n, 4 batches). 256 WGs = 256 CUs.
// R14 = compact broadcast h-buffer. Insight from R13: wall = 512 x step_path;
// occupancy/decomposition cannot shorten the chain (R13: 2-batch WG has identical
// step latency to 4-batch). The attackable term is the post-barrier LDS burst:
// 8 waves x 4 ds_read_b128 = 32KB/step through ~85B/cy pipe ~ 380cy, 75% of it
// zero pad rows. Fix WITHOUT branches (R11's mistake): MFMA A-rows are independent,
// so unused rows may hold GARBAGE - map all 64 lanes onto a compact 1KB buffer with
// batch=(row>>2). 4 lanes/group read the SAME 16B -> LDS broadcast (free, m136):
// unique traffic 32KB->8KB. Rows 4b+1..3 compute redundant copies nobody reads.
// Journal:
//   R5/R6 x-pair packing     -> +15 us (lengthened C-operand serial chain)
//   R7 lgkm-only asm barrier -> +21 us (defeated compiler scheduling)
//   R8 LDS atomicAdd pred    -> +834 us (not fire-and-forget)
//   R10 acc ping-pong + early vmem issue -> neutral (window already covered)
//   R11 exec-MASKED compact reads + 2+2 chains -> +105 us (branch/phi broke sched)
//   R12 bounds(512,4) grid 512 -> +3200 us (VGPR cap 128 -> full weight spill)
//   R13 grid 512 bounds(512,2) -> 2x (no co-residency: arch+acc VGPR > 128;
//        and co-residency cannot shorten the serial chain anyway)
template<bool BF16X>
__global__ __launch_bounds__(512, 2)
void clstm_kernel(const float* __restrict__ X,
                  const short* __restrict__ Xb,
                  const float* __restrict__ W_ih,
                  const float* __restrict__ W_hh,
                  const float* __restrict__ b_ih,
                  const float* __restrict__ b_hh,
                  const float* __restrict__ W_out,
                  const float* __restrict__ b_out,
                  float* __restrict__ out)
{
    constexpr int B = 32, T = 512, N = 32, H = 128, G = 512;  // G = 4H
    constexpr int HT_OFF = B * T * N;
    constexpr int CT_OFF = HT_OFF + N * B * H;
    constexpr int PRED_OFF = 2048;               // h buffers: 2 x 1KB compact
    constexpr float C1 = 1.4426950408889634f;    // log2(e)

    __shared__ __align__(16) unsigned char smem[2048 + 8192];  // h dbuf + pred stage

    const int tid  = threadIdx.x;
    const int w    = tid >> 6;   // wave 0..7
    const int L    = tid & 63;
    const int col  = L & 15;
    const int quad = L >> 4;
    const int n    = blockIdx.x & 31;   // series
    const int bgrp = blockIdx.x >> 5;   // batch group (4 batches)

    // ---- loop-invariant weight fragments (fp32 -> bf16, once) ----
    s16x8 Bh[4][4];  // [gate tt][kt]
    s16x8 Bx[4];     // [gate tt]  k = input p 0..31
    f32x4 biasv[4];  // persistent MFMA C operand (bias broadcast)
#pragma unroll
    for (int tt = 0; tt < 4; ++tt) {
        const int g = (w + 8 * tt) * 16 + col;
        const float* whr = W_hh + ((size_t)n * G + g) * H + quad * 8;
#pragma unroll
        for (int kt = 0; kt < 4; ++kt) {
            const float* p = whr + kt * 32;
#pragma unroll
            for (int jj = 0; jj < 8; ++jj) Bh[tt][kt][jj] = f2bf(p[jj]);
        }
        const float* wir = W_ih + ((size_t)n * G + g) * N + quad * 8;
#pragma unroll
        for (int jj = 0; jj < 8; ++jj) Bx[tt][jj] = f2bf(wir[jj]);
        const float bb = b_ih[n * G + g] + b_hh[n * G + g];
        biasv[tt] = (f32x4){bb, bb, bb, bb};
    }

    // ---- pred tile: B col 0 = W_out, rotated across waves ----
    s16x8 Bp[4];
    const float bo = b_out[n];
    const f32x4 bov = (f32x4){bo, bo, bo, bo};
#pragma unroll
    for (int kt = 0; kt < 4; ++kt) {
        const float* wp = W_out + n * H + kt * 32 + quad * 8;
#pragma unroll
        for (int jj = 0; jj < 8; ++jj)
            Bp[kt][jj] = (col == 0) ? f2bf(wp[jj]) : (short)0;
    }

    // ---- compact h layout: [kt][rq][batch][8 bf16] = kt*256 + rq*64 + b*16 + j3*2 ----
    // writer: cell (batch=quad, j=w*16+col); j = kt*32 + rq*8 + j3
    int wboff;
    {
        const int j = w * 16 + col;
        wboff = ((j >> 5) << 8) + (((j >> 3) & 3) << 6) + (quad << 4) + ((j & 7) << 1);
    }
    // reader: lane (rq=L>>4, row=col) -> batch = row>>2 (4-way same-address broadcast)
    const int raddr = ((L >> 4) << 6) + ((col >> 2) << 4);

    // ---- x loader: lanes with col%4==0 carry batch b=col>>2 at row m=col ----
    const bool xactive = (col & 3) == 0;
    const int  xb      = bgrp * 4 + (col >> 2);
    const float* xp  = X + ((size_t)xb * T) * N + quad * 8;
    const short* xbp = BF16X ? (Xb + ((size_t)xb * T) * N + quad * 8) : nullptr;

    auto loadx = [&](int t) -> s16x8 {
        s16x8 r = (s16x8)(short)0;
        if (xactive) {
            if constexpr (BF16X) {
                r = *(const s16x8*)(xbp + (size_t)t * N);
            } else {
                float4 lo = *(const float4*)(xp + (size_t)t * N);
                float4 hi = *(const float4*)(xp + (size_t)t * N + 4);
                r[0] = f2bf(lo.x); r[1] = f2bf(lo.y); r[2] = f2bf(lo.z); r[3] = f2bf(lo.w);
                r[4] = f2bf(hi.x); r[5] = f2bf(hi.y); r[6] = f2bf(hi.z); r[7] = f2bf(hi.w);
            }
        }
        return r;
    };

    // zero h buffer 0 only (h_{-1}=0); buffer 1 is fully written each step (no pad)
    if (tid < 64) *(float4*)(smem + tid * 16) = make_float4(0.f, 0.f, 0.f, 0.f);

    float cst = 0.f, hlast = 0.f;

    // prologue: accA = partial gates for t=0; prefetch x_1, x_2
    f32x4 accA[4], accB[4];
    {
        s16x8 x0 = loadx(0);
#pragma unroll
        for (int tt = 0; tt < 4; ++tt)
            accA[tt] = MFMA_B16(x0, Bx[tt], biasv[tt]);
    }
    s16x8 xA = loadx(1);
    s16x8 xB = loadx(2);

    __syncthreads();

// CUR holds x-partials (+bias) for TCUR on entry; gates accumulate in place.
// NXT computed fresh (x-partials for TCUR+1), issued first to fill the lgkm window.
#define STEP(P, TCUR, CUR, NXT)                                                     \
    {                                                                               \
        const unsigned char* rb = smem + (P) * 1024;                                \
        s16x8 Af[4];                                                                \
        _Pragma("unroll")                                                           \
        for (int kt = 0; kt < 4; ++kt)                                              \
            Af[kt] = *(const s16x8*)(rb + kt * 256 + raddr);                        \
        _Pragma("unroll")                                                           \
        for (int tt = 0; tt < 4; ++tt)                                              \
            NXT[tt] = MFMA_B16(xA, Bx[tt], biasv[tt]);                              \
        xA = xB;                                                                    \
        xB = loadx(((TCUR) + 3 < T) ? (TCUR) + 3 : T - 1);                          \
        _Pragma("unroll")                                                           \
        for (int tt = 0; tt < 4; ++tt)                                              \
            CUR[tt] = MFMA_B16(Af[0], Bh[tt][0], CUR[tt]);                          \
        _Pragma("unroll")                                                           \
        for (int kt = 1; kt < 4; ++kt) {                                            \
            _Pragma("unroll")                                                       \
            for (int tt = 0; tt < 4; ++tt)                                          \
                CUR[tt] = MFMA_B16(Af[kt], Bh[tt][kt], CUR[tt]);                    \
        }                                                                           \
        if (w == ((TCUR) & 7)) {                                                    \
            f32x4 pacc = bov;                                                       \
            _Pragma("unroll")                                                       \
            for (int kt = 0; kt < 4; ++kt)                                          \
                pacc = MFMA_B16(Af[kt], Bp[kt], pacc);                              \
            if ((TCUR) > 0 && col == 0)                                             \
                *(float*)(smem + PRED_OFF + ((quad << 9) + (TCUR) - 1) * 4) =       \
                    pacc[0];                                                        \
        }                                                                           \
        /* epilogue: fused-rcp activations (8 trans) */                             \
        {                                                                           \
            const float iv = CUR[0][0], fv = CUR[1][0];                             \
            const float gv = CUR[2][0], ov = CUR[3][0];                             \
            const float ei = exp2f(-C1 * iv);                                       \
            const float ef = exp2f(-C1 * fv);                                       \
            const float eg = exp2f(-2.0f * C1 * gv);                                \
            const float eo = exp2f(-C1 * ov);                                       \
            const float sf = rcp_f(1.0f + ef);                                      \
            const float itg = (1.0f - eg) * rcp_f((1.0f + ei) * (1.0f + eg));       \
            const float cc = __builtin_fmaf(sf, cst, itg);                          \
            cst = cc;                                                               \
            const float ec = exp2f(-2.0f * C1 * cc);                                \
            const float hv = (1.0f - ec) * rcp_f((1.0f + eo) * (1.0f + ec));        \
            hlast = hv;                                                             \
            *(short*)(smem + ((P) ^ 1) * 1024 + wboff) = f2bf(hv);                  \
        }                                                                           \
        __syncthreads();                                                            \
    }

#pragma unroll 1
    for (int t2 = 0; t2 < T; t2 += 2) {
        STEP(0, t2, accA, accB)
        STEP(1, t2 + 1, accB, accA)
    }
#undef STEP

    // ---- tail pred: t = T-1 uses h_{T-1}, sitting in buffer 0 ----
    if (w == 0) {
        f32x4 pacc = bov;
#pragma unroll
        for (int kt = 0; kt < 4; ++kt) {
            s16x8 Af = *(const s16x8*)(smem + kt * 256 + raddr);
            pacc = MFMA_B16(Af, Bp[kt], pacc);
        }
        if (col == 0)
            *(float*)(smem + PRED_OFF + ((quad << 9) + (T - 1)) * 4) = pacc[0];
    }
    __syncthreads();

    // ---- flush pred stage -> global ----
#pragma unroll
    for (int e = tid; e < 4 * T; e += 512) {
        const int b = e >> 9, t = e & (T - 1);
        out[((size_t)(bgrp * 4 + b) * T + t) * N + n] =
            *(const float*)(smem + PRED_OFF + e * 4);
    }

    // ---- final hT, cT ----
    {
        const int bglob = bgrp * 4 + quad;
        const int j = w * 16 + col;
        out[HT_OFF + ((size_t)n * B + bglob) * H + j] = hlast;
        out[CT_OFF + ((size_t)n * B + bglob) * H + j] = cst;
    }
}

extern "C" void kernel_launch(void* const* d_in, const int* in_sizes, int n_in,
                              void* d_out, int out_size, void* d_ws, size_t ws_size,
                              hipStream_t stream) {
    const float* X     = (const float*)d_in[0];
    const float* W_ih  = (const float*)d_in[1];
    const float* W_hh  = (const float*)d_in[2];
    const float* b_ih  = (const float*)d_in[3];
    const float* b_hh  = (const float*)d_in[4];
    const float* W_out = (const float*)d_in[5];
    const float* b_out = (const float*)d_in[6];
    float* out = (float*)d_out;

    const int xelems = 32 * 512 * 32;  // B*T*N
    const bool usebf = ws_size >= (size_t)xelems * sizeof(short);

    if (usebf) {
        short* Xb = (short*)d_ws;
        xcvt_kernel<<<dim3(xelems / 1024), dim3(256), 0, stream>>>(X, Xb, xelems);
        clstm_kernel<true><<<dim3(256), dim3(512), 0, stream>>>(
            X, Xb, W_ih, W_hh, b_ih, b_hh, W_out, b_out, out);
    } else {
        clstm_kernel<false><<<dim3(256), dim3(512), 0, stream>>>(
            X, nullptr, W_ih, W_hh, b_ih, b_hh, W_out, b_out, out);
    }
}